// Round 1
// baseline (582.370 us; speedup 1.0000x reference)
//
#include <hip/hip_runtime.h>
#include <hip/hip_bf16.h>

// MeshEdgeBlock fused kernel for MI355X (gfx950).
// R4: pre-pack W1/W2 into bf16 MFMA B-fragment layout (prep kernel -> d_ws).
// Removes ~1024 scalar global loads + ~1024 f32->bf16 converts per wave per
// block from the GEMM inner loops (the prior VALU/VMEM bottleneck).
//
// Structure (1 block = 128 edges, 512 threads = 8 waves):
//   X[128x384] staged (as bf16) in LDS in MFMA A-fragment chunk layout.
//   For each of 4 N-chunks of H (128 cols): GEMM1 chunk -> SiLU -> LDS,
//   then GEMM2 partial accumulate (flash-style; H never hits HBM).
//   Epilogue: +b2, LayerNorm (shfl butterfly + LDS combine), +edge residual.

typedef __bf16 bf16;
typedef __bf16 bf16x8 __attribute__((ext_vector_type(8)));
typedef float f32x4 __attribute__((ext_vector_type(4)));

#define E_TOT 250000
#define N_NODES 100000
#define ET 128
#define NBLK ((E_TOT + ET - 1) / ET)  // 1954

// ---------------------------------------------------------------------------
// Prep: pack fp32 row-major weights into bf16 B-fragment layout.
//   W1 [384,512]: W1p[((kb*4+quad)*512 + n)*8 + j] = bf16(W1[(kb*32+quad*8+j)*512 + n])
//   W2 [512,128]: W2p[((kc*4+quad)*128 + n)*8 + j] = bf16(W2[(kc*32+quad*8+j)*128 + n])
// Lane reads are then a single contiguous bf16x8 (16 B) per fragment.
// ---------------------------------------------------------------------------
__global__ __launch_bounds__(256) void pack_weights(const float* __restrict__ W1,
                                                    const float* __restrict__ W2,
                                                    bf16* __restrict__ W1p,
                                                    bf16* __restrict__ W2p) {
  int tid = blockIdx.x * blockDim.x + threadIdx.x;
  if (tid < 384 * 512) {
    int k = tid >> 9;  // row of W1
    int n = tid & 511;
    int kb = k >> 5, quad = (k >> 3) & 3, j = k & 7;
    W1p[(((kb * 4 + quad) * 512) + n) * 8 + j] = (bf16)W1[tid];
  }
  if (tid < 512 * 128) {
    int k = tid >> 7;  // row of W2
    int n = tid & 127;
    int kc = k >> 5, quad = (k >> 3) & 3, j = k & 7;
    W2p[(((kc * 4 + quad) * 128) + n) * 8 + j] = (bf16)W2[tid];
  }
}

__global__ __launch_bounds__(512, 2)
void edge_mlp_kernel(const float* __restrict__ srcf,
                     const float* __restrict__ dstf,
                     const float* __restrict__ edgef,
                     const int* __restrict__ sidx,
                     const int* __restrict__ didx,
                     const bf16* __restrict__ W1p,  // packed B-frag layout
                     const bf16* __restrict__ W2p,  // packed B-frag layout
                     const float* __restrict__ b1p,
                     const float* __restrict__ b2p,
                     const float* __restrict__ gp,
                     const float* __restrict__ bp,
                     float* __restrict__ out) {
  // Xs: 96 chunks (mt*12+kb)*512 bf16, A-frag layout: elem(m,k) at
  //     ((k%32)>>3)*128 + (m%16)*8 + (k%8) within chunk.  96 KB.
  // Hs: 32 chunks (mt*4+kb2)*512, same layout.             32 KB.
  __shared__ __align__(16) bf16 Xs[96 * 512];
  __shared__ __align__(16) bf16 Hs[32 * 512];

  const int tid = threadIdx.x;
  const int w = tid >> 6;     // wave 0..7
  const int lane = tid & 63;
  const int l15 = lane & 15;
  const int quad = lane >> 4; // 0..3
  const int h = w >> 2;       // m-half (rows h*64..h*64+63)
  const int q = w & 3;        // n-quarter (cols q*32..q*32+31)
  const long base = (long)blockIdx.x * ET;

  // ---- stage X: wave w stages edges [w*16, w*16+16), chunks kb=0..11 ----
  {
    int e = (int)base + w * 16 + l15;
    int ec = e < E_TOT ? e : (E_TOT - 1);  // clamp tail (stores guarded later)
    int si = sidx[ec];
    int di = didx[ec];
    si = si < 0 ? 0 : (si >= N_NODES ? N_NODES - 1 : si);
    di = di < 0 ? 0 : (di >= N_NODES ? N_NODES - 1 : di);
    const float* rs = srcf + (long)si * 128;
    const float* rd = dstf + (long)di * 128;
    const float* re = edgef + (long)ec * 128;
#pragma unroll
    for (int kb = 0; kb < 12; ++kb) {
      const float* rowp = (kb < 4) ? rs : ((kb < 8) ? rd : re);
      int off = ((kb & 3) << 5) + (quad << 3);  // (kb%4)*32 + quad*8
      float4 v0 = *(const float4*)(rowp + off);
      float4 v1 = *(const float4*)(rowp + off + 4);
      bf16x8 vb;
      vb[0] = (bf16)v0.x; vb[1] = (bf16)v0.y; vb[2] = (bf16)v0.z; vb[3] = (bf16)v0.w;
      vb[4] = (bf16)v1.x; vb[5] = (bf16)v1.y; vb[6] = (bf16)v1.z; vb[7] = (bf16)v1.w;
      // lane (quad*16+l15) holds elems (m=l15, k%32=quad*8..+7): pos=lane*8
      *(bf16x8*)(&Xs[(w * 12 + kb) * 512 + lane * 8]) = vb;
    }
  }

  // per-lane fixed epilogue columns: n2 = q*32 + t*16 + l15
  float b2v[2], gv[2], bv[2];
#pragma unroll
  for (int t = 0; t < 2; ++t) {
    int n2 = q * 32 + t * 16 + l15;
    b2v[t] = b2p[n2];
    gv[t] = gp[n2];
    bv[t] = bp[n2];
  }

  f32x4 acc2[4][2];
#pragma unroll
  for (int i = 0; i < 4; ++i)
#pragma unroll
    for (int t = 0; t < 2; ++t)
      acc2[i][t] = (f32x4){0.f, 0.f, 0.f, 0.f};

  __syncthreads();

  // ---- main loop: 4 chunks of 128 H-columns ----
  for (int nc = 0; nc < 4; ++nc) {
    // GEMM1 chunk: Hc[128,128] = X[128,384] @ W1[:, nc*128..]
    f32x4 acc1[4][2];
#pragma unroll
    for (int i = 0; i < 4; ++i)
#pragma unroll
      for (int t = 0; t < 2; ++t)
        acc1[i][t] = (f32x4){0.f, 0.f, 0.f, 0.f};

    float b1v[2];
#pragma unroll
    for (int t = 0; t < 2; ++t)
      b1v[t] = b1p[nc * 128 + q * 32 + t * 16 + l15];

#pragma unroll
    for (int kb = 0; kb < 12; ++kb) {
      // B-frag: single bf16x8 per (t): n = nc*128 + q*32 + t*16 + l15,
      // k = kb*32 + quad*8 + j.  Packed layout -> contiguous 16 B per lane,
      // 256 B contiguous per 16-lane group.
      const bf16* wp = W1p + (((long)(kb * 4 + quad) * 512) + nc * 128 + q * 32) * 8;
      bf16x8 b[2];
      b[0] = *(const bf16x8*)(wp + l15 * 8);
      b[1] = *(const bf16x8*)(wp + (16 + l15) * 8);
      bf16x8 a[4];
#pragma unroll
      for (int i = 0; i < 4; ++i)
        a[i] = *(const bf16x8*)(&Xs[((h * 4 + i) * 12 + kb) * 512 + lane * 8]);
#pragma unroll
      for (int i = 0; i < 4; ++i)
#pragma unroll
        for (int t = 0; t < 2; ++t)
          acc1[i][t] =
              __builtin_amdgcn_mfma_f32_16x16x32_bf16(a[i], b[t], acc1[i][t], 0, 0, 0);
    }

    __syncthreads();  // prev GEMM2 readers done before Hs overwrite

    // bias + SiLU + scatter into Hs A-frag layout.
    // D layout: row m%16 = quad*4+r, col k2%32 = t*16+l15 (kb2 chunk = q).
#pragma unroll
    for (int i = 0; i < 4; ++i)
#pragma unroll
      for (int t = 0; t < 2; ++t) {
        int pos0 = ((t * 2 + (l15 >> 3)) * 128) + (quad * 4) * 8 + (l15 & 7);
        bf16* hp = &Hs[((h * 4 + i) * 4 + q) * 512 + pos0];
#pragma unroll
        for (int r = 0; r < 4; ++r) {
          float vv = acc1[i][t][r] + b1v[t];
          float s = vv / (1.0f + __expf(-vv));  // SiLU in fp32 (safe at +/-large)
          hp[r * 8] = (bf16)s;
        }
      }
    __syncthreads();

    // GEMM2 partial: Y += Hc[128,128] @ W2[nc*128.., :]
#pragma unroll
    for (int kb2 = 0; kb2 < 4; ++kb2) {
      // B-frag: n = q*32 + t*16 + l15, k = (nc*4+kb2)*32 + quad*8 + j
      const bf16* wp =
          W2p + (((long)((nc * 4 + kb2) * 4 + quad) * 128) + q * 32) * 8;
      bf16x8 b[2];
      b[0] = *(const bf16x8*)(wp + l15 * 8);
      b[1] = *(const bf16x8*)(wp + (16 + l15) * 8);
      bf16x8 a[4];
#pragma unroll
      for (int i = 0; i < 4; ++i)
        a[i] = *(const bf16x8*)(&Hs[((h * 4 + i) * 4 + kb2) * 512 + lane * 8]);
#pragma unroll
      for (int i = 0; i < 4; ++i)
#pragma unroll
        for (int t = 0; t < 2; ++t)
          acc2[i][t] =
              __builtin_amdgcn_mfma_f32_16x16x32_bf16(a[i], b[t], acc2[i][t], 0, 0, 0);
    }
  }

  __syncthreads();  // all GEMM2 done; Hs reusable as LN scratch

  // ---- LayerNorm ----
  float* psum = (float*)Hs;      // [128][4]
  float* psq = psum + 512;       // [128][4]
  float* pmu = psq + 512;        // [128]
  float* prs = pmu + 128;        // [128]

#pragma unroll
  for (int i = 0; i < 4; ++i) {
#pragma unroll
    for (int r = 0; r < 4; ++r) {
      float v0 = acc2[i][0][r] + b2v[0];
      float v1 = acc2[i][1][r] + b2v[1];
      float s = v0 + v1;
      float ss = v0 * v0 + v1 * v1;
      // butterfly within 16-lane group -> sum of this wave's 32 cols per row
#pragma unroll
      for (int mk = 8; mk >= 1; mk >>= 1) {
        s += __shfl_xor(s, mk, 64);
        ss += __shfl_xor(ss, mk, 64);
      }
      if (l15 == 0) {
        int row = (h * 4 + i) * 16 + quad * 4 + r;
        psum[row * 4 + q] = s;
        psq[row * 4 + q] = ss;
      }
    }
  }
  __syncthreads();
  if (tid < 128) {
    float s = psum[tid * 4] + psum[tid * 4 + 1] + psum[tid * 4 + 2] + psum[tid * 4 + 3];
    float ss = psq[tid * 4] + psq[tid * 4 + 1] + psq[tid * 4 + 2] + psq[tid * 4 + 3];
    float mu = s * (1.0f / 128.0f);
    float var = fmaxf(ss * (1.0f / 128.0f) - mu * mu, 0.0f);  // cancellation-safe
    pmu[tid] = mu;
    prs[tid] = rsqrtf(var + 1e-5f);
  }
  __syncthreads();

  // ---- normalize + gamma/beta + edge residual (from Xs) + store ----
#pragma unroll
  for (int i = 0; i < 4; ++i) {
#pragma unroll
    for (int r = 0; r < 4; ++r) {
      int m = (h * 4 + i) * 16 + quad * 4 + r;
      long e = base + m;
      if (e >= E_TOT) continue;
      float mu = pmu[m];
      float rsg = prs[m];
#pragma unroll
      for (int t = 0; t < 2; ++t) {
        int n2 = q * 32 + t * 16 + l15;
        float v = acc2[i][t][r] + b2v[t];
        int posE = ((t * 2 + (l15 >> 3)) * 128) + (quad * 4 + r) * 8 + (l15 & 7);
        float ev = (float)Xs[((h * 4 + i) * 12 + 8 + q) * 512 + posE];
        float y = (v - mu) * rsg * gv[t] + bv[t] + ev;
        out[e * 128 + n2] = y;
      }
    }
  }
}

extern "C" void kernel_launch(void* const* d_in, const int* in_sizes, int n_in,
                              void* d_out, int out_size, void* d_ws, size_t ws_size,
                              hipStream_t stream) {
  const float* srcf = (const float*)d_in[0];
  const float* dstf = (const float*)d_in[1];
  const float* edgef = (const float*)d_in[2];
  const int* sidx = (const int*)d_in[3];
  const int* didx = (const int*)d_in[4];
  const float* W1 = (const float*)d_in[5];
  const float* b1 = (const float*)d_in[6];
  const float* W2 = (const float*)d_in[7];
  const float* b2 = (const float*)d_in[8];
  const float* g = (const float*)d_in[9];
  const float* be = (const float*)d_in[10];
  float* out = (float*)d_out;

  // Workspace: W1p (384 KB bf16) then W2p (128 KB bf16).
  bf16* W1p = (bf16*)d_ws;
  bf16* W2p = W1p + 384 * 512;

  // Pack weights into MFMA B-fragment layout (cheap: ~1 MB read, 512 KB write).
  pack_weights<<<(384 * 512 + 255) / 256, 256, 0, stream>>>(W1, W2, W1p, W2p);

  edge_mlp_kernel<<<NBLK, 512, 0, stream>>>(srcf, dstf, edgef, sidx, didx,
                                            W1p, W2p, b1, b2, g, be, out);
}

// Round 5
// 527.734 us; speedup vs baseline: 1.1035x; 1.1035x over previous
//
#include <hip/hip_runtime.h>
#include <hip/hip_bf16.h>

// MeshEdgeBlock fused kernel for MI355X (gfx950).
// R5 (3rd resubmit; rounds 2-4 hit GPU-acquisition timeouts, never measured).
// Occupancy fix: ET 128->64 edges/block halves LDS (128 KB -> 64 KB),
// giving 2 blocks/CU (16 waves, 4/SIMD) instead of 1 (8 waves, 2/SIMD).
// R4 counters showed MfmaUtil 13.7 / VALUBusy 25 / Occupancy 22.8 with
// LDS_Block_Size=128KB: barrier-drain latency with nothing to overlap.
//
// Structure (1 block = 64 edges, 512 threads = 8 waves):
//   X[64x384] staged (as bf16) in LDS in MFMA A-fragment chunk layout.
//   For each of 4 N-chunks of H (128 cols): GEMM1 chunk -> SiLU -> LDS,
//   then GEMM2 partial accumulate (flash-style; H never hits HBM).
//   Wave (h,q): rows h*32..+32, cols q*32..+32 (2x2 16x16 MFMA tiles).
//   Epilogue: +b2, LayerNorm (shfl butterfly + LDS combine), +edge residual.

typedef __bf16 bf16;
typedef __bf16 bf16x8 __attribute__((ext_vector_type(8)));
typedef float f32x4 __attribute__((ext_vector_type(4)));

#define E_TOT 250000
#define N_NODES 100000
#define ET 64
#define NBLK ((E_TOT + ET - 1) / ET)  // 3907

// ---------------------------------------------------------------------------
// Prep: pack fp32 row-major weights into bf16 B-fragment layout.
//   W1 [384,512]: W1p[((kb*4+quad)*512 + n)*8 + j] = bf16(W1[(kb*32+quad*8+j)*512 + n])
//   W2 [512,128]: W2p[((kc*4+quad)*128 + n)*8 + j] = bf16(W2[(kc*32+quad*8+j)*128 + n])
// Lane reads are then a single contiguous bf16x8 (16 B) per fragment.
// ---------------------------------------------------------------------------
__global__ __launch_bounds__(256) void pack_weights(const float* __restrict__ W1,
                                                    const float* __restrict__ W2,
                                                    bf16* __restrict__ W1p,
                                                    bf16* __restrict__ W2p) {
  int tid = blockIdx.x * blockDim.x + threadIdx.x;
  if (tid < 384 * 512) {
    int k = tid >> 9;  // row of W1
    int n = tid & 511;
    int kb = k >> 5, quad = (k >> 3) & 3, j = k & 7;
    W1p[(((kb * 4 + quad) * 512) + n) * 8 + j] = (bf16)W1[tid];
  }
  if (tid < 512 * 128) {
    int k = tid >> 7;  // row of W2
    int n = tid & 127;
    int kc = k >> 5, quad = (k >> 3) & 3, j = k & 7;
    W2p[(((kc * 4 + quad) * 128) + n) * 8 + j] = (bf16)W2[tid];
  }
}

__global__ __launch_bounds__(512, 4)
void edge_mlp_kernel(const float* __restrict__ srcf,
                     const float* __restrict__ dstf,
                     const float* __restrict__ edgef,
                     const int* __restrict__ sidx,
                     const int* __restrict__ didx,
                     const bf16* __restrict__ W1p,  // packed B-frag layout
                     const bf16* __restrict__ W2p,  // packed B-frag layout
                     const float* __restrict__ b1p,
                     const float* __restrict__ b2p,
                     const float* __restrict__ gp,
                     const float* __restrict__ bp,
                     float* __restrict__ out) {
  // Xs: 48 chunks (mt*12+kb)*512 bf16, A-frag layout: elem(m,k) at
  //     ((k%32)>>3)*128 + (m%16)*8 + (k%8) within chunk.  48 KB.
  // Hs: 16 chunks (mt*4+kb2)*512, same layout.             16 KB.
  __shared__ __align__(16) bf16 Xs[48 * 512];
  __shared__ __align__(16) bf16 Hs[16 * 512];

  const int tid = threadIdx.x;
  const int w = tid >> 6;     // wave 0..7
  const int lane = tid & 63;
  const int l15 = lane & 15;
  const int quad = lane >> 4; // 0..3
  const int h = w >> 2;       // m-half (rows h*32..h*32+31)
  const int q = w & 3;        // n-quarter (cols q*32..q*32+31)
  const long base = (long)blockIdx.x * ET;

  // ---- stage X: wave w handles edge group mt=w&3 (16 edges), kb-half w>>2 ----
  {
    const int mt = w & 3;
    const int half = w >> 2;  // 0: kb 0..5, 1: kb 6..11
    int e = (int)base + mt * 16 + l15;
    int ec = e < E_TOT ? e : (E_TOT - 1);  // clamp tail (stores guarded later)
    int si = sidx[ec];
    int di = didx[ec];
    si = si < 0 ? 0 : (si >= N_NODES ? N_NODES - 1 : si);
    di = di < 0 ? 0 : (di >= N_NODES ? N_NODES - 1 : di);
    const float* rs = srcf + (long)si * 128;
    const float* rd = dstf + (long)di * 128;
    const float* re = edgef + (long)ec * 128;
#pragma unroll
    for (int kk = 0; kk < 6; ++kk) {
      int kb = half * 6 + kk;
      const float* rowp = (kb < 4) ? rs : ((kb < 8) ? rd : re);
      int off = ((kb & 3) << 5) + (quad << 3);  // (kb%4)*32 + quad*8
      float4 v0 = *(const float4*)(rowp + off);
      float4 v1 = *(const float4*)(rowp + off + 4);
      bf16x8 vb;
      vb[0] = (bf16)v0.x; vb[1] = (bf16)v0.y; vb[2] = (bf16)v0.z; vb[3] = (bf16)v0.w;
      vb[4] = (bf16)v1.x; vb[5] = (bf16)v1.y; vb[6] = (bf16)v1.z; vb[7] = (bf16)v1.w;
      // lane (quad*16+l15) holds elems (m=l15, k%32=quad*8..+7): pos=lane*8
      *(bf16x8*)(&Xs[(mt * 12 + kb) * 512 + lane * 8]) = vb;
    }
  }

  // per-lane fixed epilogue columns: n2 = q*32 + t*16 + l15
  float b2v[2], gv[2], bv[2];
#pragma unroll
  for (int t = 0; t < 2; ++t) {
    int n2 = q * 32 + t * 16 + l15;
    b2v[t] = b2p[n2];
    gv[t] = gp[n2];
    bv[t] = bp[n2];
  }

  f32x4 acc2[2][2];
#pragma unroll
  for (int i = 0; i < 2; ++i)
#pragma unroll
    for (int t = 0; t < 2; ++t)
      acc2[i][t] = (f32x4){0.f, 0.f, 0.f, 0.f};

  __syncthreads();

  // ---- main loop: 4 chunks of 128 H-columns ----
  for (int nc = 0; nc < 4; ++nc) {
    // GEMM1 chunk: Hc[64,128] = X[64,384] @ W1[:, nc*128..]
    f32x4 acc1[2][2];
#pragma unroll
    for (int i = 0; i < 2; ++i)
#pragma unroll
      for (int t = 0; t < 2; ++t)
        acc1[i][t] = (f32x4){0.f, 0.f, 0.f, 0.f};

    float b1v[2];
#pragma unroll
    for (int t = 0; t < 2; ++t)
      b1v[t] = b1p[nc * 128 + q * 32 + t * 16 + l15];

#pragma unroll
    for (int kb = 0; kb < 12; ++kb) {
      // B-frag: single bf16x8 per (t): n = nc*128 + q*32 + t*16 + l15,
      // k = kb*32 + quad*8 + j.  Packed layout -> contiguous 16 B per lane.
      const bf16* wp = W1p + (((long)(kb * 4 + quad) * 512) + nc * 128 + q * 32) * 8;
      bf16x8 b[2];
      b[0] = *(const bf16x8*)(wp + l15 * 8);
      b[1] = *(const bf16x8*)(wp + (16 + l15) * 8);
      bf16x8 a[2];
#pragma unroll
      for (int i = 0; i < 2; ++i)
        a[i] = *(const bf16x8*)(&Xs[((h * 2 + i) * 12 + kb) * 512 + lane * 8]);
#pragma unroll
      for (int i = 0; i < 2; ++i)
#pragma unroll
        for (int t = 0; t < 2; ++t)
          acc1[i][t] =
              __builtin_amdgcn_mfma_f32_16x16x32_bf16(a[i], b[t], acc1[i][t], 0, 0, 0);
    }

    __syncthreads();  // prev GEMM2 readers done before Hs overwrite

    // bias + SiLU + scatter into Hs A-frag layout.
    // D layout: row m%16 = quad*4+r, col k2%32 = t*16+l15 (kb2 chunk = q).
#pragma unroll
    for (int i = 0; i < 2; ++i)
#pragma unroll
      for (int t = 0; t < 2; ++t) {
        int pos0 = ((t * 2 + (l15 >> 3)) * 128) + (quad * 4) * 8 + (l15 & 7);
        bf16* hp = &Hs[((h * 2 + i) * 4 + q) * 512 + pos0];
#pragma unroll
        for (int r = 0; r < 4; ++r) {
          float vv = acc1[i][t][r] + b1v[t];
          float s = vv / (1.0f + __expf(-vv));  // SiLU in fp32 (safe at +/-large)
          hp[r * 8] = (bf16)s;
        }
      }
    __syncthreads();

    // GEMM2 partial: Y += Hc[64,128] @ W2[nc*128.., :]
#pragma unroll
    for (int kb2 = 0; kb2 < 4; ++kb2) {
      // B-frag: n = q*32 + t*16 + l15, k = (nc*4+kb2)*32 + quad*8 + j
      const bf16* wp =
          W2p + (((long)((nc * 4 + kb2) * 4 + quad) * 128) + q * 32) * 8;
      bf16x8 b[2];
      b[0] = *(const bf16x8*)(wp + l15 * 8);
      b[1] = *(const bf16x8*)(wp + (16 + l15) * 8);
      bf16x8 a[2];
#pragma unroll
      for (int i = 0; i < 2; ++i)
        a[i] = *(const bf16x8*)(&Hs[((h * 2 + i) * 4 + kb2) * 512 + lane * 8]);
#pragma unroll
      for (int i = 0; i < 2; ++i)
#pragma unroll
        for (int t = 0; t < 2; ++t)
          acc2[i][t] =
              __builtin_amdgcn_mfma_f32_16x16x32_bf16(a[i], b[t], acc2[i][t], 0, 0, 0);
    }
  }

  __syncthreads();  // all GEMM2 done; Hs reusable as LN scratch

  // ---- LayerNorm (64 rows) ----
  float* psum = (float*)Hs;      // [64][4]
  float* psq = psum + 256;       // [64][4]
  float* pmu = psq + 256;        // [64]
  float* prs = pmu + 64;         // [64]

#pragma unroll
  for (int i = 0; i < 2; ++i) {
#pragma unroll
    for (int r = 0; r < 4; ++r) {
      float v0 = acc2[i][0][r] + b2v[0];
      float v1 = acc2[i][1][r] + b2v[1];
      float s = v0 + v1;
      float ss = v0 * v0 + v1 * v1;
      // butterfly within 16-lane group -> sum of this wave's 32 cols per row
#pragma unroll
      for (int mk = 8; mk >= 1; mk >>= 1) {
        s += __shfl_xor(s, mk, 64);
        ss += __shfl_xor(ss, mk, 64);
      }
      if (l15 == 0) {
        int row = (h * 2 + i) * 16 + quad * 4 + r;
        psum[row * 4 + q] = s;
        psq[row * 4 + q] = ss;
      }
    }
  }
  __syncthreads();
  if (tid < 64) {
    float s = psum[tid * 4] + psum[tid * 4 + 1] + psum[tid * 4 + 2] + psum[tid * 4 + 3];
    float ss = psq[tid * 4] + psq[tid * 4 + 1] + psq[tid * 4 + 2] + psq[tid * 4 + 3];
    float mu = s * (1.0f / 128.0f);
    float var = fmaxf(ss * (1.0f / 128.0f) - mu * mu, 0.0f);  // cancellation-safe
    pmu[tid] = mu;
    prs[tid] = rsqrtf(var + 1e-5f);
  }
  __syncthreads();

  // ---- normalize + gamma/beta + edge residual (from Xs) + store ----
#pragma unroll
  for (int i = 0; i < 2; ++i) {
#pragma unroll
    for (int r = 0; r < 4; ++r) {
      int m = (h * 2 + i) * 16 + quad * 4 + r;
      long e = base + m;
      if (e >= E_TOT) continue;
      float mu = pmu[m];
      float rsg = prs[m];
#pragma unroll
      for (int t = 0; t < 2; ++t) {
        int n2 = q * 32 + t * 16 + l15;
        float v = acc2[i][t][r] + b2v[t];
        int posE = ((t * 2 + (l15 >> 3)) * 128) + (quad * 4 + r) * 8 + (l15 & 7);
        float ev = (float)Xs[((h * 2 + i) * 12 + 8 + q) * 512 + posE];
        float y = (v - mu) * rsg * gv[t] + bv[t] + ev;
        out[e * 128 + n2] = y;
      }
    }
  }
}

extern "C" void kernel_launch(void* const* d_in, const int* in_sizes, int n_in,
                              void* d_out, int out_size, void* d_ws, size_t ws_size,
                              hipStream_t stream) {
  const float* srcf = (const float*)d_in[0];
  const float* dstf = (const float*)d_in[1];
  const float* edgef = (const float*)d_in[2];
  const int* sidx = (const int*)d_in[3];
  const int* didx = (const int*)d_in[4];
  const float* W1 = (const float*)d_in[5];
  const float* b1 = (const float*)d_in[6];
  const float* W2 = (const float*)d_in[7];
  const float* b2 = (const float*)d_in[8];
  const float* g = (const float*)d_in[9];
  const float* be = (const float*)d_in[10];
  float* out = (float*)d_out;

  // Workspace: W1p (384 KB bf16) then W2p (128 KB bf16).
  bf16* W1p = (bf16*)d_ws;
  bf16* W2p = W1p + 384 * 512;

  // Pack weights into MFMA B-fragment layout (cheap: ~1 MB read, 512 KB write).
  pack_weights<<<(384 * 512 + 255) / 256, 256, 0, stream>>>(W1, W2, W1p, W2p);

  edge_mlp_kernel<<<NBLK, 512, 0, stream>>>(srcf, dstf, edgef, sidx, didx,
                                            W1p, W2p, b1, b2, g, be, out);
}

// Round 6
// 475.965 us; speedup vs baseline: 1.2236x; 1.1088x over previous
//
#include <hip/hip_runtime.h>
#include <hip/hip_bf16.h>

// MeshEdgeBlock fused kernel for MI355X (gfx950).
// R6: break the inner-loop load->MFMA serialization.
// R5 counters: Occupancy 44.8 (fix landed) but MfmaUtil only 16.4, VGPR=52
// -> compiler allocated ZERO prefetch depth; every kb step stalls ~250cy on
// L2-latency B-fragment loads. Changes:
//  1) depth-2 rotating register prefetch of B-frags in GEMM1+GEMM2
//     (static kb&1 indexing under full unroll).
//  2) Hs double-buffered (16->32 KB, LDS 64->80 KB, still 2 blocks/CU):
//     one barrier per nc instead of two; GEMM1(nc+1) overlaps GEMM2(nc).
//
// Structure (1 block = 64 edges, 512 threads = 8 waves):
//   X[64x384] staged (as bf16) in LDS in MFMA A-fragment chunk layout.
//   For each of 4 N-chunks of H (128 cols): GEMM1 chunk -> SiLU -> LDS(buf),
//   then GEMM2 partial accumulate (flash-style; H never hits HBM).
//   Wave (h,q): rows h*32..+32, cols q*32..+32 (2x2 16x16 MFMA tiles).
//   Epilogue: +b2, LayerNorm (shfl butterfly + LDS combine), +edge residual.

typedef __bf16 bf16;
typedef __bf16 bf16x8 __attribute__((ext_vector_type(8)));
typedef float f32x4 __attribute__((ext_vector_type(4)));

#define E_TOT 250000
#define N_NODES 100000
#define ET 64
#define NBLK ((E_TOT + ET - 1) / ET)  // 3907

// ---------------------------------------------------------------------------
// Prep: pack fp32 row-major weights into bf16 B-fragment layout.
//   W1 [384,512]: W1p[((kb*4+quad)*512 + n)*8 + j] = bf16(W1[(kb*32+quad*8+j)*512 + n])
//   W2 [512,128]: W2p[((kc*4+quad)*128 + n)*8 + j] = bf16(W2[(kc*32+quad*8+j)*128 + n])
// Lane reads are then a single contiguous bf16x8 (16 B) per fragment.
// ---------------------------------------------------------------------------
__global__ __launch_bounds__(256) void pack_weights(const float* __restrict__ W1,
                                                    const float* __restrict__ W2,
                                                    bf16* __restrict__ W1p,
                                                    bf16* __restrict__ W2p) {
  int tid = blockIdx.x * blockDim.x + threadIdx.x;
  if (tid < 384 * 512) {
    int k = tid >> 9;  // row of W1
    int n = tid & 511;
    int kb = k >> 5, quad = (k >> 3) & 3, j = k & 7;
    W1p[(((kb * 4 + quad) * 512) + n) * 8 + j] = (bf16)W1[tid];
  }
  if (tid < 512 * 128) {
    int k = tid >> 7;  // row of W2
    int n = tid & 127;
    int kc = k >> 5, quad = (k >> 3) & 3, j = k & 7;
    W2p[(((kc * 4 + quad) * 128) + n) * 8 + j] = (bf16)W2[tid];
  }
}

__global__ __launch_bounds__(512, 4)
void edge_mlp_kernel(const float* __restrict__ srcf,
                     const float* __restrict__ dstf,
                     const float* __restrict__ edgef,
                     const int* __restrict__ sidx,
                     const int* __restrict__ didx,
                     const bf16* __restrict__ W1p,  // packed B-frag layout
                     const bf16* __restrict__ W2p,  // packed B-frag layout
                     const float* __restrict__ b1p,
                     const float* __restrict__ b2p,
                     const float* __restrict__ gp,
                     const float* __restrict__ bp,
                     float* __restrict__ out) {
  // Xs: 48 chunks (mt*12+kb)*512 bf16, A-frag layout: elem(m,k) at
  //     ((k%32)>>3)*128 + (m%16)*8 + (k%8) within chunk.  48 KB.
  // Hs: 2 buffers x 16 chunks (mt*4+kb2)*512, same layout. 32 KB.
  __shared__ __align__(16) bf16 Xs[48 * 512];
  __shared__ __align__(16) bf16 Hs[2 * 16 * 512];

  const int tid = threadIdx.x;
  const int w = tid >> 6;     // wave 0..7
  const int lane = tid & 63;
  const int l15 = lane & 15;
  const int quad = lane >> 4; // 0..3
  const int h = w >> 2;       // m-half (rows h*32..h*32+31)
  const int q = w & 3;        // n-quarter (cols q*32..q*32+31)
  const long base = (long)blockIdx.x * ET;

  // ---- stage X: wave w handles edge group mt=w&3 (16 edges), kb-half w>>2 ----
  {
    const int mt = w & 3;
    const int half = w >> 2;  // 0: kb 0..5, 1: kb 6..11
    int e = (int)base + mt * 16 + l15;
    int ec = e < E_TOT ? e : (E_TOT - 1);  // clamp tail (stores guarded later)
    int si = sidx[ec];
    int di = didx[ec];
    si = si < 0 ? 0 : (si >= N_NODES ? N_NODES - 1 : si);
    di = di < 0 ? 0 : (di >= N_NODES ? N_NODES - 1 : di);
    const float* rs = srcf + (long)si * 128;
    const float* rd = dstf + (long)di * 128;
    const float* re = edgef + (long)ec * 128;
#pragma unroll
    for (int kk = 0; kk < 6; ++kk) {
      int kb = half * 6 + kk;
      const float* rowp = (kb < 4) ? rs : ((kb < 8) ? rd : re);
      int off = ((kb & 3) << 5) + (quad << 3);  // (kb%4)*32 + quad*8
      float4 v0 = *(const float4*)(rowp + off);
      float4 v1 = *(const float4*)(rowp + off + 4);
      bf16x8 vb;
      vb[0] = (bf16)v0.x; vb[1] = (bf16)v0.y; vb[2] = (bf16)v0.z; vb[3] = (bf16)v0.w;
      vb[4] = (bf16)v1.x; vb[5] = (bf16)v1.y; vb[6] = (bf16)v1.z; vb[7] = (bf16)v1.w;
      // lane (quad*16+l15) holds elems (m=l15, k%32=quad*8..+7): pos=lane*8
      *(bf16x8*)(&Xs[(mt * 12 + kb) * 512 + lane * 8]) = vb;
    }
  }

  // per-lane fixed epilogue columns: n2 = q*32 + t*16 + l15
  float b2v[2], gv[2], bv[2];
#pragma unroll
  for (int t = 0; t < 2; ++t) {
    int n2 = q * 32 + t * 16 + l15;
    b2v[t] = b2p[n2];
    gv[t] = gp[n2];
    bv[t] = bp[n2];
  }

  f32x4 acc2[2][2];
#pragma unroll
  for (int i = 0; i < 2; ++i)
#pragma unroll
    for (int t = 0; t < 2; ++t)
      acc2[i][t] = (f32x4){0.f, 0.f, 0.f, 0.f};

  __syncthreads();

  // ---- main loop: 4 chunks of 128 H-columns ----
  for (int nc = 0; nc < 4; ++nc) {
    bf16* hbuf = &Hs[(nc & 1) * 16 * 512];  // double-buffered H chunk

    // GEMM1 chunk: Hc[64,128] = X[64,384] @ W1[:, nc*128..]
    f32x4 acc1[2][2];
#pragma unroll
    for (int i = 0; i < 2; ++i)
#pragma unroll
      for (int t = 0; t < 2; ++t)
        acc1[i][t] = (f32x4){0.f, 0.f, 0.f, 0.f};

    float b1v[2];
#pragma unroll
    for (int t = 0; t < 2; ++t)
      b1v[t] = b1p[nc * 128 + q * 32 + t * 16 + l15];

    // depth-2 rotating B-frag prefetch: bB[kb&1] holds frags for step kb.
    bf16x8 bB[2][2];
#pragma unroll
    for (int p = 0; p < 2; ++p) {
      const bf16* wp = W1p + (((long)(p * 4 + quad) * 512) + nc * 128 + q * 32) * 8;
      bB[p][0] = *(const bf16x8*)(wp + l15 * 8);
      bB[p][1] = *(const bf16x8*)(wp + (16 + l15) * 8);
    }

#pragma unroll
    for (int kb = 0; kb < 12; ++kb) {
      bf16x8 a[2];
#pragma unroll
      for (int i = 0; i < 2; ++i)
        a[i] = *(const bf16x8*)(&Xs[((h * 2 + i) * 12 + kb) * 512 + lane * 8]);
#pragma unroll
      for (int i = 0; i < 2; ++i)
#pragma unroll
        for (int t = 0; t < 2; ++t)
          acc1[i][t] = __builtin_amdgcn_mfma_f32_16x16x32_bf16(a[i], bB[kb & 1][t],
                                                              acc1[i][t], 0, 0, 0);
      if (kb < 10) {  // prefetch step kb+2 into the slot just consumed
        const bf16* wp =
            W1p + (((long)((kb + 2) * 4 + quad) * 512) + nc * 128 + q * 32) * 8;
        bB[kb & 1][0] = *(const bf16x8*)(wp + l15 * 8);
        bB[kb & 1][1] = *(const bf16x8*)(wp + (16 + l15) * 8);
      }
    }

    // bias + SiLU + scatter into hbuf A-frag layout.
    // D layout: row m%16 = quad*4+r, col k2%32 = t*16+l15 (kb2 chunk = q).
    // Safe without a pre-barrier: this nc writes buf (nc&1); concurrent
    // laggard waves read buf ((nc-1)&1) in their GEMM2.
#pragma unroll
    for (int i = 0; i < 2; ++i)
#pragma unroll
      for (int t = 0; t < 2; ++t) {
        int pos0 = ((t * 2 + (l15 >> 3)) * 128) + (quad * 4) * 8 + (l15 & 7);
        bf16* hp = &hbuf[((h * 2 + i) * 4 + q) * 512 + pos0];
#pragma unroll
        for (int r = 0; r < 4; ++r) {
          float vv = acc1[i][t][r] + b1v[t];
          float s = vv / (1.0f + __expf(-vv));  // SiLU in fp32 (safe at +/-large)
          hp[r * 8] = (bf16)s;
        }
      }
    __syncthreads();  // hbuf fully written before GEMM2 reads it

    // GEMM2 partial: Y += Hc[64,128] @ W2[nc*128.., :]
    // depth-2 rotating B-frag prefetch, same pattern as GEMM1.
    bf16x8 bC[2][2];
#pragma unroll
    for (int p = 0; p < 2; ++p) {
      const bf16* wp =
          W2p + (((long)((nc * 4 + p) * 4 + quad) * 128) + q * 32) * 8;
      bC[p][0] = *(const bf16x8*)(wp + l15 * 8);
      bC[p][1] = *(const bf16x8*)(wp + (16 + l15) * 8);
    }

#pragma unroll
    for (int kb2 = 0; kb2 < 4; ++kb2) {
      bf16x8 a[2];
#pragma unroll
      for (int i = 0; i < 2; ++i)
        a[i] = *(const bf16x8*)(&hbuf[((h * 2 + i) * 4 + kb2) * 512 + lane * 8]);
#pragma unroll
      for (int i = 0; i < 2; ++i)
#pragma unroll
        for (int t = 0; t < 2; ++t)
          acc2[i][t] = __builtin_amdgcn_mfma_f32_16x16x32_bf16(a[i], bC[kb2 & 1][t],
                                                              acc2[i][t], 0, 0, 0);
      if (kb2 < 2) {  // prefetch step kb2+2
        const bf16* wp =
            W2p + (((long)((nc * 4 + kb2 + 2) * 4 + quad) * 128) + q * 32) * 8;
        bC[kb2 & 1][0] = *(const bf16x8*)(wp + l15 * 8);
        bC[kb2 & 1][1] = *(const bf16x8*)(wp + (16 + l15) * 8);
      }
    }
    // no trailing barrier: next nc's GEMM1 touches only Xs + registers, and
    // its scatter targets the OTHER H buffer; the scatter->read barrier above
    // orders buffer reuse two nc's apart.
  }

  __syncthreads();  // all GEMM2 done; Hs reusable as LN scratch

  // ---- LayerNorm (64 rows) ----
  float* psum = (float*)Hs;      // [64][4]
  float* psq = psum + 256;       // [64][4]
  float* pmu = psq + 256;        // [64]
  float* prs = pmu + 64;         // [64]

#pragma unroll
  for (int i = 0; i < 2; ++i) {
#pragma unroll
    for (int r = 0; r < 4; ++r) {
      float v0 = acc2[i][0][r] + b2v[0];
      float v1 = acc2[i][1][r] + b2v[1];
      float s = v0 + v1;
      float ss = v0 * v0 + v1 * v1;
      // butterfly within 16-lane group -> sum of this wave's 32 cols per row
#pragma unroll
      for (int mk = 8; mk >= 1; mk >>= 1) {
        s += __shfl_xor(s, mk, 64);
        ss += __shfl_xor(ss, mk, 64);
      }
      if (l15 == 0) {
        int row = (h * 2 + i) * 16 + quad * 4 + r;
        psum[row * 4 + q] = s;
        psq[row * 4 + q] = ss;
      }
    }
  }
  __syncthreads();
  if (tid < 64) {
    float s = psum[tid * 4] + psum[tid * 4 + 1] + psum[tid * 4 + 2] + psum[tid * 4 + 3];
    float ss = psq[tid * 4] + psq[tid * 4 + 1] + psq[tid * 4 + 2] + psq[tid * 4 + 3];
    float mu = s * (1.0f / 128.0f);
    float var = fmaxf(ss * (1.0f / 128.0f) - mu * mu, 0.0f);  // cancellation-safe
    pmu[tid] = mu;
    prs[tid] = rsqrtf(var + 1e-5f);
  }
  __syncthreads();

  // ---- normalize + gamma/beta + edge residual (from Xs) + store ----
#pragma unroll
  for (int i = 0; i < 2; ++i) {
#pragma unroll
    for (int r = 0; r < 4; ++r) {
      int m = (h * 2 + i) * 16 + quad * 4 + r;
      long e = base + m;
      if (e >= E_TOT) continue;
      float mu = pmu[m];
      float rsg = prs[m];
#pragma unroll
      for (int t = 0; t < 2; ++t) {
        int n2 = q * 32 + t * 16 + l15;
        float v = acc2[i][t][r] + b2v[t];
        int posE = ((t * 2 + (l15 >> 3)) * 128) + (quad * 4 + r) * 8 + (l15 & 7);
        float ev = (float)Xs[((h * 2 + i) * 12 + 8 + q) * 512 + posE];
        float y = (v - mu) * rsg * gv[t] + bv[t] + ev;
        out[e * 128 + n2] = y;
      }
    }
  }
}

extern "C" void kernel_launch(void* const* d_in, const int* in_sizes, int n_in,
                              void* d_out, int out_size, void* d_ws, size_t ws_size,
                              hipStream_t stream) {
  const float* srcf = (const float*)d_in[0];
  const float* dstf = (const float*)d_in[1];
  const float* edgef = (const float*)d_in[2];
  const int* sidx = (const int*)d_in[3];
  const int* didx = (const int*)d_in[4];
  const float* W1 = (const float*)d_in[5];
  const float* b1 = (const float*)d_in[6];
  const float* W2 = (const float*)d_in[7];
  const float* b2 = (const float*)d_in[8];
  const float* g = (const float*)d_in[9];
  const float* be = (const float*)d_in[10];
  float* out = (float*)d_out;

  // Workspace: W1p (384 KB bf16) then W2p (128 KB bf16).
  bf16* W1p = (bf16*)d_ws;
  bf16* W2p = W1p + 384 * 512;

  // Pack weights into MFMA B-fragment layout (cheap: ~1 MB read, 512 KB write).
  pack_weights<<<(384 * 512 + 255) / 256, 256, 0, stream>>>(W1, W2, W1p, W2p);

  edge_mlp_kernel<<<NBLK, 512, 0, stream>>>(srcf, dstf, edgef, sidx, didx,
                                            W1p, W2p, b1, b2, g, be, out);
}